// Round 1
// baseline (220.549 us; speedup 1.0000x reference)
//
#include <hip/hip_runtime.h>

// pixelSNAIL causal attention, MI355X gfx950.
// B=32, N=1024 tokens, C=128 (qk dim), CM=256 (v dim), fp32 in/out.
// softmax over FULL row, then strict causal mask, then @V.
// Strategy: bf16x3 MFMA for QK^T (hi/lo split), bf16 MFMA for PV,
// fixed -40 shift instead of row-max (logits bounded ~[-66,66]).

typedef __attribute__((ext_vector_type(8))) short short8;
typedef __attribute__((ext_vector_type(4))) float floatx4;

#define MFMA16(a, b, c) __builtin_amdgcn_mfma_f32_16x16x32_bf16((a), (b), (c), 0, 0, 0)

constexpr int N  = 1024;
constexpr int C  = 128;
constexpr int CM = 256;
constexpr int BM = 64;    // query rows per block
constexpr int BN = 32;    // keys per tile
constexpr int KSTR = 136; // K tile LDS row stride (bf16 elems), 128+8 pad -> bank-balanced b128 reads
constexpr int VSTR = 40;  // V^T / P LDS row stride, 32+8 pad
constexpr int PSTR = 40;

__device__ __forceinline__ unsigned short f2bf(float x) {
    unsigned int u = __float_as_uint(x);
    u += 0x7fffu + ((u >> 16) & 1u);   // round-to-nearest-even
    return (unsigned short)(u >> 16);
}
__device__ __forceinline__ float bf2f(unsigned short h) {
    return __uint_as_float(((unsigned int)h) << 16);
}

__global__ __launch_bounds__(256, 2)
void causal_attn_kernel(const float* __restrict__ qg, const float* __restrict__ kg,
                        const float* __restrict__ vg, float* __restrict__ og)
{
    __shared__ __align__(16) unsigned short Khi[BN * KSTR];
    __shared__ __align__(16) unsigned short Klo[BN * KSTR];
    __shared__ __align__(16) unsigned short Vt[CM * VSTR];   // V^T: [cm][key]
    __shared__ __align__(16) unsigned short Pb[BM * PSTR];   // P: [qrow][key]
    __shared__ float lbuf[BM];

    const int tid = threadIdx.x;
    const int wv  = tid >> 6;    // wave 0..3
    const int ln  = tid & 63;
    const int r   = ln & 15;
    const int qd  = ln >> 4;     // quad 0..3
    const int q0  = blockIdx.x * BM;
    const int bat = blockIdx.y;

    const float* qb = qg + (size_t)bat * N * C;
    const float* kb = kg + (size_t)bat * N * C;
    const float* vb = vg + (size_t)bat * N * CM;
    float*       ob = og + (size_t)bat * N * CM;

    // ---- Q fragments in registers (wave rows q0+wv*16+r), hi/lo split ----
    short8 qhi[4], qlo[4];
    {
        const float* qr = qb + (size_t)(q0 + wv * 16 + r) * C + qd * 8;
#pragma unroll
        for (int ks = 0; ks < 4; ++ks) {
            float4 a = *(const float4*)(qr + ks * 32);
            float4 c = *(const float4*)(qr + ks * 32 + 4);
            float xs[8] = {a.x, a.y, a.z, a.w, c.x, c.y, c.z, c.w};
            short8 h, l;
#pragma unroll
            for (int j = 0; j < 8; ++j) {
                unsigned short hb = f2bf(xs[j]);
                h[j] = (short)hb;
                l[j] = (short)f2bf(xs[j] - bf2f(hb));
            }
            qhi[ks] = h;
            qlo[ks] = l;
        }
    }

    floatx4 oacc[4][4];
#pragma unroll
    for (int s = 0; s < 4; ++s)
#pragma unroll
        for (int ct = 0; ct < 4; ++ct)
            oacc[s][ct] = (floatx4){0.f, 0.f, 0.f, 0.f};
    float lsum[4] = {0.f, 0.f, 0.f, 0.f};

    const int irow = q0 + wv * 16 + qd * 4;  // this lane's S/D row (+rg)

    for (int tile = 0; tile < N / BN; ++tile) {
        const int n0 = tile * BN;
        const bool pv = (n0 <= q0 + BN);  // any j<i in this tile for this block?

        // ---- stage K tile -> LDS as bf16 hi/lo ----
#pragma unroll
        for (int i = 0; i < (BN * C / 4) / 256; ++i) {  // 4 float4 per thread
            int f = tid + i * 256;
            int row = f >> 5, c4 = f & 31;
            float4 x = *(const float4*)(kb + (size_t)(n0 + row) * C + c4 * 4);
            float xs[4] = {x.x, x.y, x.z, x.w};
            unsigned short h0 = f2bf(xs[0]), h1 = f2bf(xs[1]), h2 = f2bf(xs[2]), h3 = f2bf(xs[3]);
            unsigned int hp0 = (unsigned)h0 | ((unsigned)h1 << 16);
            unsigned int hp1 = (unsigned)h2 | ((unsigned)h3 << 16);
            unsigned int lp0 = (unsigned)f2bf(xs[0] - bf2f(h0)) | ((unsigned)f2bf(xs[1] - bf2f(h1)) << 16);
            unsigned int lp1 = (unsigned)f2bf(xs[2] - bf2f(h2)) | ((unsigned)f2bf(xs[3] - bf2f(h3)) << 16);
            *(uint2*)(&Khi[row * KSTR + c4 * 4]) = make_uint2(hp0, hp1);
            *(uint2*)(&Klo[row * KSTR + c4 * 4]) = make_uint2(lp0, lp1);
        }
        // ---- stage V tile -> LDS transposed bf16 (only if this tile feeds PV) ----
        if (pv) {
            int kblk = tid & 7;         // key 4-block
            int cb0  = tid >> 3;        // cm 4-block
#pragma unroll
            for (int i = 0; i < 2; ++i) {
                int cb = cb0 + i * 32;
                const float* vrow = vb + (size_t)(n0 + kblk * 4) * CM + cb * 4;
                float4 x0 = *(const float4*)(vrow);
                float4 x1 = *(const float4*)(vrow + CM);
                float4 x2 = *(const float4*)(vrow + 2 * CM);
                float4 x3 = *(const float4*)(vrow + 3 * CM);
                float m0[4] = {x0.x, x0.y, x0.z, x0.w};
                float m1[4] = {x1.x, x1.y, x1.z, x1.w};
                float m2[4] = {x2.x, x2.y, x2.z, x2.w};
                float m3[4] = {x3.x, x3.y, x3.z, x3.w};
#pragma unroll
                for (int d = 0; d < 4; ++d) {
                    unsigned int p0 = (unsigned)f2bf(m0[d]) | ((unsigned)f2bf(m1[d]) << 16);
                    unsigned int p1 = (unsigned)f2bf(m2[d]) | ((unsigned)f2bf(m3[d]) << 16);
                    *(uint2*)(&Vt[(cb * 4 + d) * VSTR + kblk * 4]) = make_uint2(p0, p1);
                }
            }
        }
        __syncthreads();

        // ---- QK^T (bf16x3) + exp + denom accumulation + masked P write ----
#pragma unroll
        for (int t = 0; t < 2; ++t) {
            floatx4 acc = (floatx4){0.f, 0.f, 0.f, 0.f};
            const int kt = t * 16 + r;  // B-frag n index = key within tile
#pragma unroll
            for (int ks = 0; ks < 4; ++ks) {
                short8 bh = *(const short8*)(&Khi[kt * KSTR + ks * 32 + qd * 8]);
                short8 bl = *(const short8*)(&Klo[kt * KSTR + ks * 32 + qd * 8]);
                acc = MFMA16(qhi[ks], bh, acc);
                acc = MFMA16(qlo[ks], bh, acc);
                acc = MFMA16(qhi[ks], bl, acc);
            }
            const int jglob = n0 + t * 16 + r;  // C-layout col = key
#pragma unroll
            for (int rg = 0; rg < 4; ++rg) {
                float p = __expf(acc[rg] - 40.0f);
                lsum[rg] += p;  // full-row denominator: UNMASKED
                if (pv) {
                    float pm = (jglob < irow + rg) ? p : 0.0f;  // strict causal
                    Pb[(wv * 16 + qd * 4 + rg) * PSTR + t * 16 + r] = f2bf(pm);
                }
            }
        }

        if (pv) {
            __syncthreads();  // P visible to all waves
            short8 ap[4];
#pragma unroll
            for (int s = 0; s < 4; ++s)
                ap[s] = *(const short8*)(&Pb[(s * 16 + r) * PSTR + qd * 8]);
#pragma unroll
            for (int ct = 0; ct < 4; ++ct) {
                short8 bv = *(const short8*)(&Vt[(wv * 64 + ct * 16 + r) * VSTR + qd * 8]);
#pragma unroll
                for (int s = 0; s < 4; ++s)
                    oacc[s][ct] = MFMA16(ap[s], bv, oacc[s][ct]);
            }
        }
        __syncthreads();  // protect K/V/P LDS before next tile's staging
    }

    // ---- reduce row sums across the 16 lanes of each quad-group ----
#pragma unroll
    for (int rg = 0; rg < 4; ++rg) {
        float vsum = lsum[rg];
        vsum += __shfl_xor(vsum, 1);
        vsum += __shfl_xor(vsum, 2);
        vsum += __shfl_xor(vsum, 4);
        vsum += __shfl_xor(vsum, 8);
        lsum[rg] = vsum;
    }
    if (r == 0) {
#pragma unroll
        for (int rg = 0; rg < 4; ++rg)
            lbuf[wv * 16 + qd * 4 + rg] = lsum[rg];
    }
    __syncthreads();

    // ---- divide by denominator and store ----
#pragma unroll
    for (int s = 0; s < 4; ++s) {
        float inv[4];
#pragma unroll
        for (int rg = 0; rg < 4; ++rg)
            inv[rg] = 1.0f / lbuf[s * 16 + qd * 4 + rg];
#pragma unroll
        for (int ct = 0; ct < 4; ++ct) {
#pragma unroll
            for (int rg = 0; rg < 4; ++rg) {
                ob[(size_t)(q0 + s * 16 + qd * 4 + rg) * CM + wv * 64 + ct * 16 + r]
                    = oacc[s][ct][rg] * inv[rg];
            }
        }
    }
}

extern "C" void kernel_launch(void* const* d_in, const int* in_sizes, int n_in,
                              void* d_out, int out_size, void* d_ws, size_t ws_size,
                              hipStream_t stream) {
    const float* q = (const float*)d_in[0];
    const float* k = (const float*)d_in[1];
    const float* v = (const float*)d_in[2];
    float* o = (float*)d_out;
    (void)d_ws; (void)ws_size; (void)n_in; (void)in_sizes; (void)out_size;
    dim3 grid(N / BM, 32);  // 16 q-tiles x 32 batches = 512 blocks
    causal_attn_kernel<<<grid, dim3(256), 0, stream>>>(q, k, v, o);
}

// Round 2
// 174.952 us; speedup vs baseline: 1.2606x; 1.2606x over previous
//
#include <hip/hip_runtime.h>

// pixelSNAIL causal attention, MI355X gfx950.
// B=32, N=1024, C=128, CM=256, fp32 in/out.
// softmax over FULL row, strict causal mask, then @V.
// R2: prepass converts K (bf16 hi/lo) and V (bf16) into MFMA-B-fragment order
// in d_ws; main kernel stages tiles via global_load_lds (16B), wave-private P
// transform (no cross-wave barrier), 4 blocks/CU, XCD-aware batch placement.

typedef __attribute__((ext_vector_type(8))) short short8;
typedef __attribute__((ext_vector_type(4))) float floatx4;

#define MFMA16(a, b, c) __builtin_amdgcn_mfma_f32_16x16x32_bf16((a), (b), (c), 0, 0, 0)

constexpr int N = 1024, C = 128, CM = 256, BATCH = 32;
constexpr int BM = 32;             // q rows per block
constexpr int BN = 32;             // keys per tile
constexpr int NT = N / BN;         // 32 tiles
constexpr int KFRAG = BN * C;      // 4096 bf16 per K tile (hi or lo)
constexpr int VFRAG = BN * CM;     // 8192 bf16 per V tile
constexpr int PSTR = 40;           // P LDS row stride (bf16), 80B = 16B aligned

__device__ __forceinline__ unsigned short f2bf(float x) {
    unsigned int u = __float_as_uint(x);
    u += 0x7fffu + ((u >> 16) & 1u);   // RNE
    return (unsigned short)(u >> 16);
}
__device__ __forceinline__ float bf2f(unsigned short h) {
    return __uint_as_float(((unsigned int)h) << 16);
}
__device__ __forceinline__ uint4 pack8(const unsigned short* s) {
    uint4 u;
    u.x = (unsigned)s[0] | ((unsigned)s[1] << 16);
    u.y = (unsigned)s[2] | ((unsigned)s[3] << 16);
    u.z = (unsigned)s[4] | ((unsigned)s[5] << 16);
    u.w = (unsigned)s[6] | ((unsigned)s[7] << 16);
    return u;
}
__device__ __forceinline__ void gl2lds16(const unsigned short* g, unsigned short* l) {
    __builtin_amdgcn_global_load_lds(
        (const __attribute__((address_space(1))) void*)g,
        (__attribute__((address_space(3))) void*)l, 16, 0, 0);
}

// ---------------- prepass: K -> Khi/Klo frags, V -> V frags ----------------
// Khi/Klo frag order per tile: chunk = ((t*4+ks)*64 + ln), elem j:
//   K[key = tile*32 + t*16 + (ln&15)][c = ks*32 + (ln>>4)*8 + j]
// V frag order per tile: chunk = (ct*64 + ln), elem j:
//   V[key = tile*32 + (ln>>4)*8 + j][cm = ct*16 + (ln&15)]
__global__ __launch_bounds__(256, 4)
void prep_kernel(const float* __restrict__ kg, const float* __restrict__ vg,
                 unsigned short* __restrict__ khi, unsigned short* __restrict__ klo,
                 unsigned short* __restrict__ vf)
{
    constexpr int KP = 132;  // fp32 LDS stride for K tile rows
    constexpr int VP = 260;  // fp32 LDS stride for V tile rows
    __shared__ __align__(16) float S[BN * VP];  // 33280 B

    const int tid = threadIdx.x;
    const int tile = blockIdx.x, bat = blockIdx.y;
    const int n0 = tile * BN;
    const float* kb = kg + (size_t)bat * N * C;
    const float* vb = vg + (size_t)bat * N * CM;

    // K tile -> LDS fp32 (coalesced)
#pragma unroll
    for (int i = 0; i < 4; ++i) {
        int f = tid + i * 256;             // 1024 float4
        int row = f >> 5, c4 = f & 31;
        float4 x = *(const float4*)(kb + (size_t)(n0 + row) * C + c4 * 4);
        *(float4*)(&S[row * KP + c4 * 4]) = x;
    }
    __syncthreads();
    {
        unsigned short* khb = khi + ((size_t)bat * NT + tile) * KFRAG;
        unsigned short* klb = klo + ((size_t)bat * NT + tile) * KFRAG;
#pragma unroll
        for (int i = 0; i < 2; ++i) {
            int ch = tid + i * 256;        // 512 chunks of 8 elems
            int r = ch & 15, qd = (ch >> 4) & 3, ks = (ch >> 6) & 3, t = ch >> 8;
            const float* src = &S[(t * 16 + r) * KP + ks * 32 + qd * 8];
            unsigned short hi[8], lo[8];
#pragma unroll
            for (int j = 0; j < 8; ++j) {
                float x = src[j];
                unsigned short h = f2bf(x);
                hi[j] = h;
                lo[j] = f2bf(x - bf2f(h));
            }
            *(uint4*)(khb + (size_t)ch * 8) = pack8(hi);
            *(uint4*)(klb + (size_t)ch * 8) = pack8(lo);
        }
    }
    __syncthreads();
    // V tile -> LDS fp32
#pragma unroll
    for (int i = 0; i < 8; ++i) {
        int f = tid + i * 256;             // 2048 float4
        int row = f >> 6, c4 = f & 63;
        float4 x = *(const float4*)(vb + (size_t)(n0 + row) * CM + c4 * 4);
        *(float4*)(&S[row * VP + c4 * 4]) = x;
    }
    __syncthreads();
    {
        unsigned short* vfb = vf + ((size_t)bat * NT + tile) * VFRAG;
#pragma unroll
        for (int i = 0; i < 4; ++i) {
            int ch = tid + i * 256;        // 1024 chunks
            int r = ch & 15, qd = (ch >> 4) & 3, ct = ch >> 6;
            unsigned short o[8];
#pragma unroll
            for (int j = 0; j < 8; ++j)
                o[j] = f2bf(S[(qd * 8 + j) * VP + ct * 16 + r]);
            *(uint4*)(vfb + (size_t)ch * 8) = pack8(o);
        }
    }
}

// ---------------- main attention kernel ----------------
__global__ __launch_bounds__(256, 4)
void attn_kernel(const float* __restrict__ qg, float* __restrict__ og,
                 const unsigned short* __restrict__ khi,
                 const unsigned short* __restrict__ klo,
                 const unsigned short* __restrict__ vf)
{
    __shared__ __align__(16) unsigned short sKhi[KFRAG];     // 8 KB
    __shared__ __align__(16) unsigned short sKlo[KFRAG];     // 8 KB
    __shared__ __align__(16) unsigned short sV[VFRAG];       // 16 KB
    __shared__ __align__(16) unsigned short sP[4 * 16 * PSTR]; // 5 KB

    const int tid = threadIdx.x;
    const int w = tid >> 6, ln = tid & 63;
    const int r = ln & 15, qd = ln >> 4;
    const int rowgrp = w >> 1;      // wave pair shares 16 rows
    const int cmhalf = w & 1;       // and splits CM
    const int bat = blockIdx.x;     // batch on x: same-batch blocks share XCD L2
    const int qt = blockIdx.y;
    const int q0 = qt * BM;

    const float* qb = qg + (size_t)bat * N * C;
    float* ob = og + (size_t)bat * N * CM;
    const unsigned short* khb = khi + (size_t)bat * NT * KFRAG;
    const unsigned short* klb = klo + (size_t)bat * NT * KFRAG;
    const unsigned short* vfb = vf + (size_t)bat * NT * VFRAG;

    // Q fragments for rows q0 + rowgrp*16 + r (hi/lo split, once per block)
    short8 qhi[4], qlo[4];
    {
        const float* qr = qb + (size_t)(q0 + rowgrp * 16 + r) * C + qd * 8;
#pragma unroll
        for (int ks = 0; ks < 4; ++ks) {
            float4 a = *(const float4*)(qr + ks * 32);
            float4 b = *(const float4*)(qr + ks * 32 + 4);
            float xs[8] = {a.x, a.y, a.z, a.w, b.x, b.y, b.z, b.w};
            short8 h, l;
#pragma unroll
            for (int j = 0; j < 8; ++j) {
                unsigned short hb = f2bf(xs[j]);
                h[j] = (short)hb;
                l[j] = (short)f2bf(xs[j] - bf2f(hb));
            }
            qhi[ks] = h;
            qlo[ks] = l;
        }
    }

    floatx4 oacc[8];
#pragma unroll
    for (int ct = 0; ct < 8; ++ct) oacc[ct] = (floatx4){0.f, 0.f, 0.f, 0.f};
    float lsum[4] = {0.f, 0.f, 0.f, 0.f};
    const int irow = q0 + rowgrp * 16 + qd * 4;
    unsigned short* wP = &sP[w * 16 * PSTR];   // wave-private P buffer

    for (int tile = 0; tile < NT; ++tile) {
        const bool pv = (tile <= qt);  // block-uniform

        // ---- stage tile via global_load_lds (frag order = contiguous) ----
        {
            const unsigned short* sk = khb + (size_t)tile * KFRAG;
            gl2lds16(sk + (size_t)tid * 8,         &sKhi[tid * 8]);
            gl2lds16(sk + (size_t)(tid + 256) * 8, &sKhi[(tid + 256) * 8]);
            const unsigned short* sl = klb + (size_t)tile * KFRAG;
            gl2lds16(sl + (size_t)tid * 8,         &sKlo[tid * 8]);
            gl2lds16(sl + (size_t)(tid + 256) * 8, &sKlo[(tid + 256) * 8]);
            if (pv) {
                const unsigned short* sv = vfb + (size_t)tile * VFRAG;
#pragma unroll
                for (int i = 0; i < 4; ++i)
                    gl2lds16(sv + (size_t)(tid + i * 256) * 8, &sV[(tid + i * 256) * 8]);
            }
        }
        __syncthreads();   // staging visible (drains vmcnt)

        // ---- QK^T bf16x3 + exp + denom + masked P (wave-private) ----
#pragma unroll
        for (int t = 0; t < 2; ++t) {
            floatx4 acc = (floatx4){0.f, 0.f, 0.f, 0.f};
#pragma unroll
            for (int ks = 0; ks < 4; ++ks) {
                short8 bh = *(const short8*)(&sKhi[(((t * 4 + ks) * 64) + ln) * 8]);
                short8 bl = *(const short8*)(&sKlo[(((t * 4 + ks) * 64) + ln) * 8]);
                acc = MFMA16(qhi[ks], bh, acc);
                acc = MFMA16(qlo[ks], bh, acc);
                acc = MFMA16(qhi[ks], bl, acc);
            }
            const int jglob = tile * BN + t * 16 + r;
#pragma unroll
            for (int rg = 0; rg < 4; ++rg) {
                float p = __expf(acc[rg] - 40.0f);
                lsum[rg] += p;                       // full-row denominator
                if (pv) {
                    float pm = (jglob < irow + rg) ? p : 0.0f;  // strict causal
                    wP[(qd * 4 + rg) * PSTR + t * 16 + r] = f2bf(pm);
                }
            }
        }

        // ---- PV: wave-private P round-trip, CM half per wave ----
        if (pv) {
            asm volatile("s_waitcnt lgkmcnt(0)" ::: "memory");  // wP writes done (same wave)
            short8 ap = *(const short8*)(&wP[r * PSTR + qd * 8]);
#pragma unroll
            for (int ct = 0; ct < 8; ++ct) {
                int ctg = cmhalf * 8 + ct;
                short8 bv = *(const short8*)(&sV[(ctg * 64 + ln) * 8]);
                oacc[ct] = MFMA16(ap, bv, oacc[ct]);
            }
        }
        __syncthreads();   // all reads done before next tile's staging
    }

    // ---- denominator: reduce across 16 key-lanes ----
#pragma unroll
    for (int rg = 0; rg < 4; ++rg) {
        float v = lsum[rg];
        v += __shfl_xor(v, 1);
        v += __shfl_xor(v, 2);
        v += __shfl_xor(v, 4);
        v += __shfl_xor(v, 8);
        lsum[rg] = v;
    }

    // ---- divide + store ----
#pragma unroll
    for (int rg = 0; rg < 4; ++rg) {
        float inv = 1.0f / lsum[rg];
        float* orow = ob + (size_t)(q0 + rowgrp * 16 + qd * 4 + rg) * CM + cmhalf * 128;
#pragma unroll
        for (int ct = 0; ct < 8; ++ct)
            orow[ct * 16 + r] = oacc[ct][rg] * inv;
    }
}

extern "C" void kernel_launch(void* const* d_in, const int* in_sizes, int n_in,
                              void* d_out, int out_size, void* d_ws, size_t ws_size,
                              hipStream_t stream) {
    const float* q = (const float*)d_in[0];
    const float* k = (const float*)d_in[1];
    const float* v = (const float*)d_in[2];
    float* o = (float*)d_out;
    (void)n_in; (void)in_sizes; (void)out_size; (void)ws_size;

    unsigned short* khi = (unsigned short*)d_ws;                       // 8 MB
    unsigned short* klo = khi + (size_t)BATCH * NT * KFRAG;            // 8 MB
    unsigned short* vf  = klo + (size_t)BATCH * NT * KFRAG;            // 16 MB

    prep_kernel<<<dim3(NT, BATCH), dim3(256), 0, stream>>>(k, v, khi, klo, vf);
    attn_kernel<<<dim3(BATCH, N / BM), dim3(256), 0, stream>>>(q, o, khi, klo, vf);
}

// Round 3
// 159.792 us; speedup vs baseline: 1.3802x; 1.0949x over previous
//
#include <hip/hip_runtime.h>

// pixelSNAIL causal attention, MI355X gfx950.
// B=32, N=1024, C=128, CM=256, fp32 in/out.
// softmax over FULL row, strict causal mask, then @V.
// R3: BM=64 (wave owns 16 rows x full CM); AITER-style pipelined staging:
// K double-buffered, issued one tile ahead, partial s_waitcnt vmcnt(4) + raw
// s_barrier so the prefetch stays in flight across the barrier. Prep kernel
// has no LDS / no barriers (direct strided reads, coalesced frag writes).

typedef __attribute__((ext_vector_type(8))) short short8;
typedef __attribute__((ext_vector_type(4))) float floatx4;

#define MFMA16(a, b, c) __builtin_amdgcn_mfma_f32_16x16x32_bf16((a), (b), (c), 0, 0, 0)

constexpr int N = 1024, C = 128, CM = 256, BATCH = 32;
constexpr int BM = 64;             // q rows per block (4 waves x 16 rows)
constexpr int BN = 32;             // keys per tile
constexpr int NT = N / BN;         // 32 tiles
constexpr int KFRAG = BN * C;      // 4096 bf16 per K tile (hi or lo)
constexpr int VFRAG = BN * CM;     // 8192 bf16 per V tile
constexpr int PSTR = 40;           // P LDS row stride (bf16): 80 B rows, 16B-aligned b128 reads

__device__ __forceinline__ unsigned short f2bf(float x) {
    unsigned int u = __float_as_uint(x);
    u += 0x7fffu + ((u >> 16) & 1u);   // RNE
    return (unsigned short)(u >> 16);
}
__device__ __forceinline__ float bf2f(unsigned short h) {
    return __uint_as_float(((unsigned int)h) << 16);
}
__device__ __forceinline__ uint4 pack8(const unsigned short* s) {
    uint4 u;
    u.x = (unsigned)s[0] | ((unsigned)s[1] << 16);
    u.y = (unsigned)s[2] | ((unsigned)s[3] << 16);
    u.z = (unsigned)s[4] | ((unsigned)s[5] << 16);
    u.w = (unsigned)s[6] | ((unsigned)s[7] << 16);
    return u;
}
__device__ __forceinline__ void gl2lds16(const unsigned short* g, unsigned short* l) {
    __builtin_amdgcn_global_load_lds(
        (const __attribute__((address_space(1))) void*)g,
        (__attribute__((address_space(3))) void*)l, 16, 0, 0);
}

// ---------------- prepass: no LDS, no barriers ----------------
// Khi/Klo frag order per tile: chunk ch = (t*4+ks)*64 + ln, elem j:
//   K[key = tile*32 + t*16 + (ch&15)][c = ks*32 + ((ch>>4)&3)*8 + j]
// V frag order per tile: chunk ch = ct*64 + ln, elem j:
//   V[key = tile*32 + ((ch>>4)&3)*8 + j][cm = ct*16 + (ch&15)]
__global__ __launch_bounds__(256, 8)
void prep_kernel(const float* __restrict__ kg, const float* __restrict__ vg,
                 unsigned short* __restrict__ khi, unsigned short* __restrict__ klo,
                 unsigned short* __restrict__ vf)
{
    const int tid = threadIdx.x;
    const int tile = blockIdx.x, bat = blockIdx.y;
    const int n0 = tile * BN;
    const float* kb = kg + (size_t)bat * N * C;
    const float* vb = vg + (size_t)bat * N * CM;
    unsigned short* khb = khi + ((size_t)bat * NT + tile) * KFRAG;
    unsigned short* klb = klo + ((size_t)bat * NT + tile) * KFRAG;
    unsigned short* vfb = vf + ((size_t)bat * NT + tile) * VFRAG;

    // K: 512 chunks, 2 per thread. Reads: 32B/lane contiguous, rows 512B apart
    // (each K byte read exactly once per block; L1/L2 absorbs segmenting).
#pragma unroll
    for (int i = 0; i < 2; ++i) {
        int ch = tid + i * 256;
        int r = ch & 15, qd = (ch >> 4) & 3, ks = (ch >> 6) & 3, t = ch >> 8;
        const float* src = kb + (size_t)(n0 + t * 16 + r) * C + ks * 32 + qd * 8;
        float4 a = *(const float4*)src;
        float4 b = *(const float4*)(src + 4);
        float xs[8] = {a.x, a.y, a.z, a.w, b.x, b.y, b.z, b.w};
        unsigned short hi[8], lo[8];
#pragma unroll
        for (int j = 0; j < 8; ++j) {
            unsigned short h = f2bf(xs[j]);
            hi[j] = h;
            lo[j] = f2bf(xs[j] - bf2f(h));
        }
        *(uint4*)(khb + (size_t)ch * 8) = pack8(hi);
        *(uint4*)(klb + (size_t)ch * 8) = pack8(lo);
    }
    // V: 1024 chunks, 4 per thread. Transposed reads: per j, 4 rows x 64B
    // contiguous segments; every V byte read exactly once per block.
#pragma unroll
    for (int i = 0; i < 4; ++i) {
        int ch = tid + i * 256;
        int r = ch & 15, qd = (ch >> 4) & 3, ct = ch >> 6;
        const float* src = vb + (size_t)(n0 + qd * 8) * CM + ct * 16 + r;
        unsigned short o[8];
#pragma unroll
        for (int j = 0; j < 8; ++j)
            o[j] = f2bf(src[(size_t)j * CM]);
        *(uint4*)(vfb + (size_t)ch * 8) = pack8(o);
    }
}

// ---------------- main attention kernel ----------------
__global__ __launch_bounds__(256, 2)
void attn_kernel(const float* __restrict__ qg, float* __restrict__ og,
                 const unsigned short* __restrict__ khi,
                 const unsigned short* __restrict__ klo,
                 const unsigned short* __restrict__ vf)
{
    __shared__ __align__(16) unsigned short sKhi[2][KFRAG];  // 16 KB dbuf
    __shared__ __align__(16) unsigned short sKlo[2][KFRAG];  // 16 KB dbuf
    __shared__ __align__(16) unsigned short sV[VFRAG];       // 16 KB
    __shared__ __align__(16) unsigned short sP[4 * 16 * PSTR]; // 5 KB

    const int tid = threadIdx.x;
    const int w = tid >> 6, ln = tid & 63;
    const int r = ln & 15, qd = ln >> 4;
    const int bat = blockIdx.x;   // batch on x: linear%8 = bat%8 -> same XCD per batch
    const int qt = blockIdx.y;
    const int q0 = qt * BM;

    const float* qb = qg + (size_t)bat * N * C;
    float* ob = og + (size_t)bat * N * CM;
    const unsigned short* khb = khi + (size_t)bat * NT * KFRAG;
    const unsigned short* klb = klo + (size_t)bat * NT * KFRAG;
    const unsigned short* vfb = vf + (size_t)bat * NT * VFRAG;

    // Q fragments for this wave's 16 rows (q0 + w*16 + r), hi/lo split
    short8 qhi[4], qlo[4];
    {
        const float* qr = qb + (size_t)(q0 + w * 16 + r) * C + qd * 8;
#pragma unroll
        for (int ks = 0; ks < 4; ++ks) {
            float4 a = *(const float4*)(qr + ks * 32);
            float4 b = *(const float4*)(qr + ks * 32 + 4);
            float xs[8] = {a.x, a.y, a.z, a.w, b.x, b.y, b.z, b.w};
            short8 h, l;
#pragma unroll
            for (int j = 0; j < 8; ++j) {
                unsigned short hb = f2bf(xs[j]);
                h[j] = (short)hb;
                l[j] = (short)f2bf(xs[j] - bf2f(hb));
            }
            qhi[ks] = h;
            qlo[ks] = l;
        }
    }

    floatx4 oacc[16];
#pragma unroll
    for (int ct = 0; ct < 16; ++ct) oacc[ct] = (floatx4){0.f, 0.f, 0.f, 0.f};
    float lsum[4] = {0.f, 0.f, 0.f, 0.f};
    const int irow = q0 + w * 16 + qd * 4;
    unsigned short* wP = &sP[w * 16 * PSTR];   // wave-private P buffer

    // prologue: prefetch K tile 0 into buffer 0 (4 loads/thread)
    gl2lds16(khb + (size_t)tid * 8,         &sKhi[0][tid * 8]);
    gl2lds16(khb + (size_t)(tid + 256) * 8, &sKhi[0][(tid + 256) * 8]);
    gl2lds16(klb + (size_t)tid * 8,         &sKlo[0][tid * 8]);
    gl2lds16(klb + (size_t)(tid + 256) * 8, &sKlo[0][(tid + 256) * 8]);

    for (int tile = 0; tile < NT; ++tile) {
        const bool pvt = (tile <= 2 * qt + 1);   // tile holds keys < some row in block
        const int cb = tile & 1;

        // issue V(t) (single-buffered; prior readers cleared by last post-barrier)
        if (pvt) {
            const unsigned short* vs = vfb + (size_t)tile * VFRAG;
#pragma unroll
            for (int i = 0; i < 4; ++i)
                gl2lds16(vs + (size_t)(tid + i * 256) * 8, &sV[(tid + i * 256) * 8]);
        }
        // issue K(t+1) into the other buffer — stays in flight across the barrier
        if (tile + 1 < NT) {
            const unsigned short* k1 = khb + (size_t)(tile + 1) * KFRAG;
            const unsigned short* l1 = klb + (size_t)(tile + 1) * KFRAG;
            unsigned short* dh = &sKhi[cb ^ 1][0];
            unsigned short* dl = &sKlo[cb ^ 1][0];
            gl2lds16(k1 + (size_t)tid * 8,         dh + tid * 8);
            gl2lds16(k1 + (size_t)(tid + 256) * 8, dh + (tid + 256) * 8);
            gl2lds16(l1 + (size_t)tid * 8,         dl + tid * 8);
            gl2lds16(l1 + (size_t)(tid + 256) * 8, dl + (tid + 256) * 8);
            // drain K(t)+V(t); leave the 4 K(t+1) loads in flight
            asm volatile("s_waitcnt vmcnt(4)" ::: "memory");
        } else {
            asm volatile("s_waitcnt vmcnt(0)" ::: "memory");
        }
        asm volatile("s_barrier" ::: "memory");   // all waves' K(t)/V(t) staged

        // ---- QK^T bf16x3, 3 independent chains ----
#pragma unroll
        for (int t = 0; t < 2; ++t) {
            floatx4 a0 = (floatx4){0.f, 0.f, 0.f, 0.f};
            floatx4 a1 = (floatx4){0.f, 0.f, 0.f, 0.f};
            floatx4 a2 = (floatx4){0.f, 0.f, 0.f, 0.f};
#pragma unroll
            for (int ks = 0; ks < 4; ++ks) {
                short8 bh = *(const short8*)(&sKhi[cb][(((t * 4 + ks) * 64) + ln) * 8]);
                short8 bl = *(const short8*)(&sKlo[cb][(((t * 4 + ks) * 64) + ln) * 8]);
                a0 = MFMA16(qhi[ks], bh, a0);
                a1 = MFMA16(qlo[ks], bh, a1);
                a2 = MFMA16(qhi[ks], bl, a2);
            }
            const int jglob = tile * BN + t * 16 + r;
#pragma unroll
            for (int rg = 0; rg < 4; ++rg) {
                float s = a0[rg] + a1[rg] + a2[rg];
                float p = __expf(s - 40.0f);
                lsum[rg] += p;                               // full-row denominator
                if (pvt) {
                    float pm = (jglob < irow + rg) ? p : 0.0f;  // strict causal
                    wP[(qd * 4 + rg) * PSTR + t * 16 + r] = f2bf(pm);
                }
            }
        }

        // ---- PV: wave-private P (one A-frag), full CM=256 per wave ----
        if (pvt) {
            asm volatile("s_waitcnt lgkmcnt(0)" ::: "memory");  // wP writes landed
            short8 ap = *(const short8*)(&wP[r * PSTR + qd * 8]);
#pragma unroll
            for (int ct = 0; ct < 16; ++ct) {
                short8 bv = *(const short8*)(&sV[(ct * 64 + ln) * 8]);
                oacc[ct] = MFMA16(ap, bv, oacc[ct]);
            }
        }
        asm volatile("s_barrier" ::: "memory");   // readers done before next overwrite
    }

    // ---- denominator: reduce across the 16 key-lanes ----
#pragma unroll
    for (int rg = 0; rg < 4; ++rg) {
        float v = lsum[rg];
        v += __shfl_xor(v, 1);
        v += __shfl_xor(v, 2);
        v += __shfl_xor(v, 4);
        v += __shfl_xor(v, 8);
        lsum[rg] = v;
    }

    // ---- divide + store ----
#pragma unroll
    for (int rg = 0; rg < 4; ++rg) {
        float inv = 1.0f / lsum[rg];
        float* orow = ob + (size_t)(q0 + w * 16 + qd * 4 + rg) * CM;
#pragma unroll
        for (int ct = 0; ct < 16; ++ct)
            orow[ct * 16 + r] = oacc[ct][rg] * inv;
    }
}

extern "C" void kernel_launch(void* const* d_in, const int* in_sizes, int n_in,
                              void* d_out, int out_size, void* d_ws, size_t ws_size,
                              hipStream_t stream) {
    const float* q = (const float*)d_in[0];
    const float* k = (const float*)d_in[1];
    const float* v = (const float*)d_in[2];
    float* o = (float*)d_out;
    (void)n_in; (void)in_sizes; (void)out_size; (void)ws_size;

    unsigned short* khi = (unsigned short*)d_ws;                       // 8 MB
    unsigned short* klo = khi + (size_t)BATCH * NT * KFRAG;            // 8 MB
    unsigned short* vf  = klo + (size_t)BATCH * NT * KFRAG;            // 16 MB

    prep_kernel<<<dim3(NT, BATCH), dim3(256), 0, stream>>>(k, v, khi, klo, vf);
    attn_kernel<<<dim3(BATCH, N / BM), dim3(256), 0, stream>>>(q, o, khi, klo, vf);
}